// Round 3
// baseline (129.707 us; speedup 1.0000x reference)
//
#include <hip/hip_runtime.h>
#include <hip/hip_bf16.h>

#define NFEA 128
#define NCLS 5
#define LN_EPS 1e-5f
#define WCHUNK 64   // atoms per wave-slab

// Prep: zero seg_sum and build slab -> owning-segment map.
// Slab j's owner is the unique s with j*WCHUNK in [start_s, end_s).
__global__ __launch_bounds__(256) void prep_kernel(
    const int2* __restrict__ idx,
    int*  __restrict__ seg_of_slab,     // [nslab]
    float* __restrict__ seg_sum,        // [n_crys][128]
    int n_crys)
{
    const int t    = blockIdx.x * 256 + threadIdx.x;
    const int nthr = gridDim.x * 256;

    float4* z = (float4*)seg_sum;
    const int nz = n_crys * NFEA / 4;
    for (int i = t; i < nz; i += nthr) z[i] = make_float4(0.f, 0.f, 0.f, 0.f);

    if (t < n_crys) {
        const int2 se = idx[t];
        int j = (se.x + WCHUNK - 1) / WCHUNK;
        for (; j * WCHUNK < se.y; ++j) seg_of_slab[j] = t;
    }
}

// Kernel A: one independent wave per 64-atom slab. No barriers, no search.
// Lanes: al = lane>>5 (atom row parity), fc = lane&31 (float4 column).
__global__ __launch_bounds__(256) void seg_partial_kernel(
    const float* __restrict__ fea,       // [N_ATOMS][128]
    const int2*  __restrict__ idx,
    const int*   __restrict__ seg_of_slab,
    float* __restrict__ seg_sum)         // [N_CRYS][128]
{
    const int gw   = (blockIdx.x * 256 + threadIdx.x) >> 6;  // wave id = slab id
    const int lane = threadIdx.x & 63;
    const int fc   = lane & 31;
    const int al   = lane >> 5;
    const int a0   = gw * WCHUNK;
    const int a1   = a0 + WCHUNK;

    int s = seg_of_slab[gw];
    const float4* __restrict__ fea4 = (const float4*)fea;

    int rs = a0;
    while (rs < a1) {
        const int re = min(idx[s].y, a1);

        float4 acc0 = make_float4(0.f,0.f,0.f,0.f);
        float4 acc1 = make_float4(0.f,0.f,0.f,0.f);
        float4 acc2 = make_float4(0.f,0.f,0.f,0.f);
        float4 acc3 = make_float4(0.f,0.f,0.f,0.f);

        int a = rs + al;
        if (a + 6 < re) {
            // manual 2-stage pipeline, 4 loads in flight
            float4 v0 = fea4[(size_t)a       * 32 + fc];
            float4 v1 = fea4[(size_t)(a + 2) * 32 + fc];
            float4 v2 = fea4[(size_t)(a + 4) * 32 + fc];
            float4 v3 = fea4[(size_t)(a + 6) * 32 + fc];
            a += 8;
            for (; a + 6 < re; a += 8) {
                float4 n0 = fea4[(size_t)a       * 32 + fc];
                float4 n1 = fea4[(size_t)(a + 2) * 32 + fc];
                float4 n2 = fea4[(size_t)(a + 4) * 32 + fc];
                float4 n3 = fea4[(size_t)(a + 6) * 32 + fc];
                acc0.x += v0.x; acc0.y += v0.y; acc0.z += v0.z; acc0.w += v0.w;
                acc1.x += v1.x; acc1.y += v1.y; acc1.z += v1.z; acc1.w += v1.w;
                acc2.x += v2.x; acc2.y += v2.y; acc2.z += v2.z; acc2.w += v2.w;
                acc3.x += v3.x; acc3.y += v3.y; acc3.z += v3.z; acc3.w += v3.w;
                v0 = n0; v1 = n1; v2 = n2; v3 = n3;
            }
            acc0.x += v0.x; acc0.y += v0.y; acc0.z += v0.z; acc0.w += v0.w;
            acc1.x += v1.x; acc1.y += v1.y; acc1.z += v1.z; acc1.w += v1.w;
            acc2.x += v2.x; acc2.y += v2.y; acc2.z += v2.z; acc2.w += v2.w;
            acc3.x += v3.x; acc3.y += v3.y; acc3.z += v3.z; acc3.w += v3.w;
        }
        for (; a < re; a += 2) {
            float4 v = fea4[(size_t)a * 32 + fc];
            acc0.x += v.x; acc0.y += v.y; acc0.z += v.z; acc0.w += v.w;
        }

        // fold 4 accumulators
        acc0.x += acc1.x + acc2.x + acc3.x;
        acc0.y += acc1.y + acc2.y + acc3.y;
        acc0.z += acc1.z + acc2.z + acc3.z;
        acc0.w += acc1.w + acc2.w + acc3.w;

        // combine the two atom-lanes (lane ^ 32) in-register
        acc0.x += __shfl_xor(acc0.x, 32);
        acc0.y += __shfl_xor(acc0.y, 32);
        acc0.z += __shfl_xor(acc0.z, 32);
        acc0.w += __shfl_xor(acc0.w, 32);

        if (lane < 32) {
            float* dst = &seg_sum[(size_t)s * NFEA + lane * 4];
            atomicAdd(dst + 0, acc0.x);
            atomicAdd(dst + 1, acc0.y);
            atomicAdd(dst + 2, acc0.z);
            atomicAdd(dst + 3, acc0.w);
        }
        rs = re; ++s;
    }
}

// Kernel B: one wave per crystal (4 crystals per 256-thread block).
__global__ __launch_bounds__(256) void finalize_kernel(
    const float* __restrict__ seg_sum,  // [N_CRYS][128]
    const int2*  __restrict__ idx,
    const float* __restrict__ lnw,
    const float* __restrict__ lnb,
    const float* __restrict__ outw,     // [5][128]
    const float* __restrict__ outb,     // [5]
    float* __restrict__ out_cls,        // [N_CRYS][5]
    float* __restrict__ out_act)        // [N_CRYS][128]
{
    const int c   = (blockIdx.x * 256 + threadIdx.x) >> 6;
    const int tid = threadIdx.x & 63;
    const int2 se = idx[c];
    const float inv_len = 1.f / (float)(se.y - se.x);

    float p0 = seg_sum[(size_t)c * NFEA + tid]      * inv_len;
    float p1 = seg_sum[(size_t)c * NFEA + tid + 64] * inv_len;

    float t = p0 + p1;
    #pragma unroll
    for (int off = 32; off; off >>= 1) t += __shfl_xor(t, off);
    const float mu = t * (1.f / NFEA);

    const float d0 = p0 - mu, d1 = p1 - mu;
    float v = d0 * d0 + d1 * d1;
    #pragma unroll
    for (int off = 32; off; off >>= 1) v += __shfl_xor(v, off);
    const float rstd = rsqrtf(v * (1.f / NFEA) + LN_EPS);

    const float x0 = d0 * rstd * lnw[tid]      + lnb[tid];
    const float x1 = d1 * rstd * lnw[tid + 64] + lnb[tid + 64];
    const float a0 = (x0 > 0.f) ? x0 + log1pf(expf(-x0)) : log1pf(expf(x0));
    const float a1 = (x1 > 0.f) ? x1 + log1pf(expf(-x1)) : log1pf(expf(x1));

    out_act[(size_t)c * NFEA + tid]      = a0;
    out_act[(size_t)c * NFEA + tid + 64] = a1;

    #pragma unroll
    for (int k = 0; k < NCLS; ++k) {
        float p = a0 * outw[k * NFEA + tid] + a1 * outw[k * NFEA + tid + 64];
        #pragma unroll
        for (int off = 32; off; off >>= 1) p += __shfl_xor(p, off);
        if (tid == k) out_cls[(size_t)c * NCLS + k] = p + outb[k];
    }
}

extern "C" void kernel_launch(void* const* d_in, const int* in_sizes, int n_in,
                              void* d_out, int out_size, void* d_ws, size_t ws_size,
                              hipStream_t stream) {
    const float* fea  = (const float*)d_in[0];   // [1048576][128] f32
    const int2*  idx  = (const int2*)d_in[1];    // [8192][2] i32
    const float* lnw  = (const float*)d_in[2];
    const float* lnb  = (const float*)d_in[3];
    const float* outw = (const float*)d_in[4];
    const float* outb = (const float*)d_in[5];

    const int n_crys  = in_sizes[1] / 2;         // 8192
    const int n_atoms = in_sizes[0] / NFEA;      // 1048576
    const int nslab   = n_atoms / WCHUNK;        // 16384

    float* seg_sum     = (float*)d_ws;                                   // 4 MB
    int*   seg_of_slab = (int*)((char*)d_ws + (size_t)n_crys * NFEA * sizeof(float));

    float* out_cls = (float*)d_out;                          // 8192*5
    float* out_act = (float*)d_out + (size_t)n_crys * NCLS;  // 8192*128

    prep_kernel<<<128, 256, 0, stream>>>(idx, seg_of_slab, seg_sum, n_crys);
    seg_partial_kernel<<<nslab / 4, 256, 0, stream>>>(fea, idx, seg_of_slab, seg_sum);
    finalize_kernel<<<n_crys / 4, 256, 0, stream>>>(seg_sum, idx, lnw, lnb, outw, outb,
                                                    out_cls, out_act);
}